// Round 5
// baseline (266.813 us; speedup 1.0000x reference)
//
#include <hip/hip_runtime.h>

// SpecNCutout: out = select(mask, mean(x), x)
// x: (B=128, H=256, W=1024, C=1) fp32. mask = union of 5 clipped rects/batch.
//
// R4 bisect: three consecutive container failures with the NT-builtin
// version vs. a clean pass for the plain-float4 version. This round keeps
// ONLY the structural change (row-structured pass 1 + skip stores of
// fully-hole float4s -> those pixels are written once, by pass 2) and
// reverts all NT builtins / ext_vector typedefs / unroll pragmas to the
// exact idioms of the last-passing kernel.
// Pass 2 fills hole spans with mean; it first reduces the 2048 partials
// with the identical tree as before (bit-identical mean, absmax 0.0).
// Kernel traffic: 134 MB read + ~103 MB write (pass 1) + ~30 MB write (pass 2).

#define BB 128
#define HH 256
#define WW 1024
#define N_HOLES 5
#define HOLE_MINW (WW / 10)   // 102
#define HOLE_MINH (HH / 10)   // 25
#define N_ELEM (BB * HH * WW) // 33554432
#define ROWS_PER_BLOCK 16
#define RED_BLOCKS (BB * HH / ROWS_PER_BLOCK)  // 2048
#define ROW_SLICES 8          // fill parallelism per hole

// Pass 1: copy x->out (skipping fully-hole float4s) while accumulating sum.
// Block blk handles rows [blk*16, blk*16+16) — all within batch b = blk>>4.
__global__ __launch_bounds__(256) void copy_reduce_kernel(
    const float* __restrict__ x, float* __restrict__ out,
    const int* __restrict__ xs, const int* __restrict__ ys,
    const int* __restrict__ xs_w_raw, const int* __restrict__ ys_h_raw,
    const float* __restrict__ act_rand,
    float* __restrict__ partials) {
  int blk = blockIdx.x;
  int b = blk >> 4;                 // 256/16 = 16 blocks per batch
  int row0 = blk * ROWS_PER_BLOCK;  // global row = b*HH + h

  // Per-block (batch-uniform) hole rects.
  int ys_s[N_HOLES], ys_e[N_HOLES], xlo[N_HOLES], xhi[N_HOLES];
  #pragma unroll
  for (int n = 0; n < N_HOLES; ++n) {
    int base = b * N_HOLES + n;
    int cx = xs[base];
    int cy = ys[base];
    int hw = (xs_w_raw[base] + HOLE_MINW) >> 1;  // xs_w // 2
    int hh = (ys_h_raw[base] + HOLE_MINH) >> 1;  // ys_h // 2
    bool act = act_rand[base] < 1.0f;            // PROB = 1.0
    int yss = min(max(cy - hh, 0), HH - 2);
    int yse = min(max(cy + hh, 1), HH - 1);
    ys_s[n] = act ? yss : 1;
    ys_e[n] = act ? yse : 0;                     // empty if inactive
    xlo[n] = min(max(cx - hw, 0), WW - 2);
    xhi[n] = min(max(cx + hw, 1), WW - 1);
  }

  const float4* x4 = (const float4*)x;
  float4* out4 = (float4*)out;
  int tid = threadIdx.x;
  int w0 = tid * 4;                 // W=1024 = 256 threads * 4

  float s = 0.0f;
  for (int rr = 0; rr < ROWS_PER_BLOCK; ++rr) {
    int row = row0 + rr;
    int h = row & (HH - 1);
    long i = (long)row * (WW / 4) + tid;
    float4 v = x4[i];
    s += (v.x + v.y) + (v.z + v.w);

    // Is this thread's whole float4 inside the hole union?
    bool all_hole = true;
    #pragma unroll
    for (int j = 0; j < 4; ++j) {
      int w = w0 + j;
      bool m = false;
      #pragma unroll
      for (int n = 0; n < N_HOLES; ++n) {
        bool in_row = (ys_s[n] <= h) && (h <= ys_e[n]);
        m = m || (in_row && (xlo[n] <= w) && (w <= xhi[n]));
      }
      all_hole = all_hole && m;
    }
    if (!all_hole) out4[i] = v;
  }

  #pragma unroll
  for (int off = 32; off > 0; off >>= 1) s += __shfl_down(s, off, 64);
  __shared__ float wsum[4];
  int lane = threadIdx.x & 63;
  int wave = threadIdx.x >> 6;
  if (lane == 0) wsum[wave] = s;
  __syncthreads();
  if (threadIdx.x == 0)
    partials[blockIdx.x] = (wsum[0] + wsum[1]) + (wsum[2] + wsum[3]);
}

// Pass 2: write mean into hole spans. One block per (batch, hole, row-slice).
// Each block privately reduces the 2048 partials (8 KiB, L2-broadcast) with
// the identical tree as the old finalize_kernel -> bit-identical mean.
__global__ __launch_bounds__(256) void fill_holes_kernel(
    const int* __restrict__ xs, const int* __restrict__ ys,
    const int* __restrict__ xs_w_raw, const int* __restrict__ ys_h_raw,
    const float* __restrict__ act_rand,
    const float* __restrict__ partials,
    float* __restrict__ out) {
  float s = 0.0f;
  for (int i = threadIdx.x; i < RED_BLOCKS; i += 256) s += partials[i];
  #pragma unroll
  for (int off = 32; off > 0; off >>= 1) s += __shfl_down(s, off, 64);
  __shared__ float wsum[4];
  __shared__ float mean_sh;
  int lane = threadIdx.x & 63;
  int wave = threadIdx.x >> 6;
  if (lane == 0) wsum[wave] = s;
  __syncthreads();
  if (threadIdx.x == 0) {
    float t = (wsum[0] + wsum[1]) + (wsum[2] + wsum[3]);
    mean_sh = t * (1.0f / (float)N_ELEM);
  }
  __syncthreads();
  float mean = mean_sh;

  int bid = blockIdx.x;
  int b = bid / (N_HOLES * ROW_SLICES);
  int rem = bid % (N_HOLES * ROW_SLICES);
  int n = rem / ROW_SLICES;
  int slice = rem % ROW_SLICES;

  int base = b * N_HOLES + n;
  if (!(act_rand[base] < 1.0f)) return;          // PROB = 1.0, always true
  int cx = xs[base];
  int cy = ys[base];
  int hw = (xs_w_raw[base] + HOLE_MINW) >> 1;
  int hh = (ys_h_raw[base] + HOLE_MINH) >> 1;
  int ys_s = min(max(cy - hh, 0), HH - 2);
  int ys_e = min(max(cy + hh, 1), HH - 1);
  int xs_s = min(max(cx - hw, 0), WW - 2);
  int xs_e = min(max(cx + hw, 1), WW - 1);

  // Overlapping holes double-write the same bit pattern: race-free.
  for (int h = ys_s + slice; h <= ys_e; h += ROW_SLICES) {
    long rowbase = (long)(b * HH + h) * WW;
    for (int w = xs_s + (int)threadIdx.x; w <= xs_e; w += 256) {
      out[rowbase + w] = mean;
    }
  }
}

extern "C" void kernel_launch(void* const* d_in, const int* in_sizes, int n_in,
                              void* d_out, int out_size, void* d_ws, size_t ws_size,
                              hipStream_t stream) {
  const float* x        = (const float*)d_in[0];
  const int* xs         = (const int*)d_in[1];
  const int* ys         = (const int*)d_in[2];
  const int* xs_w_raw   = (const int*)d_in[3];
  const int* ys_h_raw   = (const int*)d_in[4];
  const float* act_rand = (const float*)d_in[5];
  float* out = (float*)d_out;

  float* partials = (float*)d_ws;                // RED_BLOCKS floats

  copy_reduce_kernel<<<RED_BLOCKS, 256, 0, stream>>>(
      x, out, xs, ys, xs_w_raw, ys_h_raw, act_rand, partials);
  fill_holes_kernel<<<BB * N_HOLES * ROW_SLICES, 256, 0, stream>>>(
      xs, ys, xs_w_raw, ys_h_raw, act_rand, partials, out);
}